// Round 12
// baseline (156.469 us; speedup 1.0000x reference)
//
#include <hip/hip_runtime.h>

typedef _Float16 half8 __attribute__((ext_vector_type(8)));
typedef __fp16 fp16x2 __attribute__((ext_vector_type(2)));
typedef float float4_t __attribute__((ext_vector_type(4)));
typedef float float2_t __attribute__((ext_vector_type(2)));
typedef float float16_t __attribute__((ext_vector_type(16)));

// ws fp16 element offsets
#define OFF_W1 0         // [4 mt][64 lane][8 j]; k=(lane>>5)*8+j natural; k=6 = b1
#define OFF_WH 2048      // 4 layers x [8 kc][4 mt][64 lane][8 j], k-permuted (pi)
#define OFF_W4 67584     // 2 chains x [8 kc][64 lane][8 j], k-permuted
#define OFF_BC 75776     // fp32[512]: [layer][mt][h][reg] C-frag-order biases
#define WS_HELEMS 75776

#define SCL_TANH 2.8853900817779268f   // 2*log2(e)
#define SCL_SIG  -1.4426950408889634f  // -log2(e)

__device__ __forceinline__ float tanh_pre(float a) {   // input pre-scaled by 2log2e
  float e = __builtin_amdgcn_exp2f(a);
  return fmaf(-2.f, __builtin_amdgcn_rcpf(1.f + e), 1.f);
}
__device__ __forceinline__ float16_t zero16() {
  float16_t z;
#pragma unroll
  for (int i = 0; i < 16; ++i) z[i] = 0.f;
  return z;
}
// tanh(acc[base..base+7] + bias) packed to half8 (= next layer's B chunk)
__device__ __forceinline__ half8 tp8(const float16_t& a, int base,
                                     float4_t ba, float4_t bb) {
  fp16x2 p0 = __builtin_amdgcn_cvt_pkrtz(tanh_pre(a[base + 0] + ba[0]),
                                         tanh_pre(a[base + 1] + ba[1]));
  fp16x2 p1 = __builtin_amdgcn_cvt_pkrtz(tanh_pre(a[base + 2] + ba[2]),
                                         tanh_pre(a[base + 3] + ba[3]));
  fp16x2 p2 = __builtin_amdgcn_cvt_pkrtz(tanh_pre(a[base + 4] + bb[0]),
                                         tanh_pre(a[base + 5] + bb[1]));
  fp16x2 p3 = __builtin_amdgcn_cvt_pkrtz(tanh_pre(a[base + 6] + bb[2]),
                                         tanh_pre(a[base + 7] + bb[3]));
  half8 r;
  r[0] = (_Float16)p0[0]; r[1] = (_Float16)p0[1];
  r[2] = (_Float16)p1[0]; r[3] = (_Float16)p1[1];
  r[4] = (_Float16)p2[0]; r[5] = (_Float16)p2[1];
  r[6] = (_Float16)p3[0]; r[7] = (_Float16)p3[1];
  return r;
}

// k-permutation tying C-layout to B-layout: r = row index in natural W
__device__ __forceinline__ int kperm(int kc, int hh, int j) {
  return 32 * (kc >> 1) + 8 * ((kc & 1) * 2 + (j >> 2)) + 4 * hh + (j & 3);
}

__global__ void prepack(const float* __restrict__ w1, const float* __restrict__ w21,
                        const float* __restrict__ w22, const float* __restrict__ wm1,
                        const float* __restrict__ wm2, const float* __restrict__ w31,
                        const float* __restrict__ w32, const float* __restrict__ b1,
                        const float* __restrict__ b21, const float* __restrict__ b22,
                        const float* __restrict__ bm1, const float* __restrict__ bm2,
                        _Float16* __restrict__ ws) {
  const int stride = gridDim.x * blockDim.x;
  for (int i = blockIdx.x * blockDim.x + threadIdx.x; i < WS_HELEMS; i += stride) {
    float v;
    if (i < OFF_WH) {                       // W1 natural k; bias at k=6 (x[6]=1)
      int j = i & 7, t = i >> 3, lane = t & 63, mt = t >> 6;
      int m = mt * 32 + (lane & 31), k = (lane >> 5) * 8 + j;
      v = (k < 6) ? w1[m * 6 + k] * SCL_TANH
        : (k == 6) ? b1[m] * SCL_TANH : 0.f;
    } else if (i < OFF_W4) {                // hidden layers, k-permuted
      int t = i - OFF_WH;
      int l = t >> 14; t &= 16383;
      int j = t & 7, t2 = t >> 3, lane = t2 & 63, t3 = t2 >> 6;
      int mt = t3 & 3, kc = t3 >> 2;
      int m = mt * 32 + (lane & 31), hh = lane >> 5;
      int r = kperm(kc, hh, j);
      const float* src = (l == 0) ? w21 : (l == 1) ? w22 : (l == 2) ? wm1 : wm2;
      v = src[m * 128 + r] * SCL_TANH;
    } else {                                // L4 A-frags, k-permuted, 2 chains
      int t = i - OFF_W4;
      int j = t & 7, t2 = t >> 3, lane = t2 & 63, t3 = t2 >> 6;
      int kc = t3 & 7, c = t3 >> 3;
      int m = lane & 31, hh = lane >> 5;
      int r = kperm(kc, hh, j);
      if (c == 0) v = (m < 3) ? w31[m * 128 + r] : 0.f;
      else        v = (m < 2) ? w32[m * 128 + r] * SCL_SIG : 0.f;
    }
    ws[i] = (_Float16)v;
  }
  float* bws = (float*)(ws + OFF_BC);       // biases in C-frag register order
  for (int i = blockIdx.x * blockDim.x + threadIdx.x; i < 512; i += stride) {
    int l = i >> 7, t = i & 127, mt = t >> 5, q = t & 31, hh = q >> 4, reg = q & 15;
    int row = mt * 32 + 8 * (reg >> 2) + 4 * hh + (reg & 3);
    const float* src = (l == 0) ? b21 : (l == 1) ? b22 : (l == 2) ? bm1 : bm2;
    bws[i] = src[row] * SCL_TANH;
  }
}

// one hidden layer, fully in-register: Bin (8 chunks) -> Bout (8 chunks)
__device__ __forceinline__ void hidden(const _Float16* __restrict__ W,
                                       const float* __restrict__ biasL,
                                       const half8* __restrict__ Bin,
                                       half8* __restrict__ Bout, int lo, int hh) {
  float16_t acc[4];
#pragma unroll
  for (int mt = 0; mt < 4; ++mt) acc[mt] = zero16();
#pragma unroll
  for (int kc = 0; kc < 8; ++kc) {
    const _Float16* p = W + kc * 2048 + lo;
#pragma unroll
    for (int mt = 0; mt < 4; ++mt) {
      half8 a = *(const half8*)(p + mt * 512);
      acc[mt] = __builtin_amdgcn_mfma_f32_32x32x16_f16(a, Bin[kc], acc[mt], 0, 0, 0);
    }
  }
  const float* bp = biasL + hh * 16;
#pragma unroll
  for (int mt = 0; mt < 4; ++mt) {
    float4_t b0 = *(const float4_t*)(bp + mt * 32);
    float4_t b1v = *(const float4_t*)(bp + mt * 32 + 4);
    float4_t b2 = *(const float4_t*)(bp + mt * 32 + 8);
    float4_t b3 = *(const float4_t*)(bp + mt * 32 + 12);
    Bout[2 * mt]     = tp8(acc[mt], 0, b0, b1v);
    Bout[2 * mt + 1] = tp8(acc[mt], 8, b2, b3);
  }
}

__device__ __forceinline__ float16_t chain8(const _Float16* __restrict__ A,
                                            const half8* __restrict__ Bin, int lo) {
  float16_t c = zero16();
#pragma unroll
  for (int kc = 0; kc < 8; ++kc) {
    half8 a = *(const half8*)(A + kc * 512 + lo);
    c = __builtin_amdgcn_mfma_f32_32x32x16_f16(a, Bin[kc], c, 0, 0, 0);
  }
  return c;
}

// Wave-autonomous: 32 samples/wave, no LDS, no barriers. VGPR cap 256
// ((256,2)) — r8/r11 lesson: a tight cap spills, and spill is fatal.
__global__ __launch_bounds__(256, 2) void bnet_main(
    const float* __restrict__ x, const float* __restrict__ meang,
    const float* __restrict__ stdg, const float* __restrict__ b31,
    const float* __restrict__ b32, const _Float16* __restrict__ ws,
    float* __restrict__ out) {
  const int lane = threadIdx.x & 63;
  const int hh = lane >> 5;
  const int s = blockIdx.x * 128 + (threadIdx.x >> 6) * 32 + (lane & 31);
  const int lo = lane * 8;
  const float* biasC = (const float*)(ws + OFF_BC);

  // ---- x load (h=0 lanes carry features; h=1 rows are zero-padded K) ----
  float xr0 = 0.f, xr1 = 0.f, xr2 = 0.f, xr3 = 0.f, xr4 = 0.f, xr5 = 0.f;
  half8 bx;
#pragma unroll
  for (int j = 0; j < 8; ++j) bx[j] = (_Float16)0.f;
  if (hh == 0) {
    const float* xp = x + (size_t)s * 6;
    float2_t e0 = *(const float2_t*)(xp);
    float2_t e1 = *(const float2_t*)(xp + 2);
    float2_t e2 = *(const float2_t*)(xp + 4);
    xr0 = e0[0]; xr1 = e0[1]; xr2 = e1[0]; xr3 = e1[1]; xr4 = e2[0]; xr5 = e2[1];
    bx[0] = (_Float16)xr0; bx[1] = (_Float16)xr1; bx[2] = (_Float16)xr2;
    bx[3] = (_Float16)xr3; bx[4] = (_Float16)xr4; bx[5] = (_Float16)xr5;
    bx[6] = (_Float16)1.f;                       // bias row (k=6)
  }

  // ---- L1 (bias folded via k=6): 4 MFMA -> actH ----
  half8 actH[8];
  {
    float16_t a[4];
#pragma unroll
    for (int mt = 0; mt < 4; ++mt) {
      half8 w = *(const half8*)(ws + OFF_W1 + mt * 512 + lo);
      a[mt] = __builtin_amdgcn_mfma_f32_32x32x16_f16(w, bx, zero16(), 0, 0, 0);
    }
    float4_t z4 = (float4_t){0.f, 0.f, 0.f, 0.f};
#pragma unroll
    for (int mt = 0; mt < 4; ++mt) {
      actH[2 * mt]     = tp8(a[mt], 0, z4, z4);
      actH[2 * mt + 1] = tp8(a[mt], 8, z4, z4);
    }
  }

  // ---- hidden layers, all in registers ----
  half8 act21[8], act22[8], actM1[8], actM2[8];
  hidden(ws + OFF_WH +     0, biasC +   0, actH,  act21, lo, hh);
  hidden(ws + OFF_WH + 16384, biasC + 128, actH,  act22, lo, hh);
  hidden(ws + OFF_WH + 32768, biasC + 256, act21, actM1, lo, hh);
  hidden(ws + OFF_WH + 49152, biasC + 384, act22, actM2, lo, hh);

  // ---- L4: two 8-MFMA chains ----
  float16_t c0 = chain8(ws + OFF_W4,        actM1, lo);
  float16_t c1 = chain8(ws + OFF_W4 + 4096, actM2, lo);

  // ---- QP epilogue: h=0 lanes own rows 0..3 (u in c0[0..2], sig in c1[0..1]) ----
  if (hh == 0) {
    float u0 = -(c0[0] + b31[0]);
    float u1 = -(c0[1] + b31[1]);
    float u2 = -(c0[2] + b31[2]);
    float p0 = 4.f * __builtin_amdgcn_rcpf(
                   1.f + __builtin_amdgcn_exp2f(c1[0] + b32[0] * SCL_SIG));
    float p1 = 4.f * __builtin_amdgcn_rcpf(
                   1.f + __builtin_amdgcn_exp2f(c1[1] + b32[1] * SCL_SIG));
    float px = xr0 * stdg[0] + meang[0], vx = xr1 * stdg[1] + meang[1];
    float py = xr2 * stdg[2] + meang[2], vy = xr3 * stdg[3] + meang[3];
    float pz = xr4 * stdg[4] + meang[4], vz = xr5 * stdg[5] + meang[5];
    float dx = px - 10.f, dy = py - 10.f, dz = pz - 9.f;
    float dx2 = dx * dx, dy2 = dy * dy, dz2 = dz * dz;
    float dx3 = dx2 * dx, dy3 = dy2 * dy, dz3 = dz2 * dz;
    float barrier = dx3 * dx + dy3 * dy + dz3 * dz - 2401.f;   // R^4
    float bdot = 4.f * (dx3 * vx + dy3 * vy + dz3 * vz);
    float Lf2b = 12.f * (dx2 * vx * vx + dy2 * vy * vy + dz2 * vz * vz);
    float g0 = -4.f * dx3, g1 = -4.f * dy3, g2 = -4.f * dz3;
    float hv = Lf2b + (p0 + p1) * bdot + p0 * p1 * barrier;
    float Gu = g0 * u0 + g1 * u1 + g2 * u2;
    float GG = g0 * g0 + g1 * g1 + g2 * g2;
    float lam = fmaxf(Gu - hv, 0.f) / GG;
    float* op = out + (size_t)s * 3;
    op[0] = u0 - lam * g0;
    op[1] = u1 - lam * g1;
    op[2] = u2 - lam * g2;
  }
}

extern "C" void kernel_launch(void* const* d_in, const int* in_sizes, int n_in,
                              void* d_out, int out_size, void* d_ws, size_t ws_size,
                              hipStream_t stream) {
  const float* x    = (const float*)d_in[0];
  const float* mean = (const float*)d_in[1];
  const float* stdv = (const float*)d_in[2];
  const float* w1   = (const float*)d_in[3];
  const float* b1   = (const float*)d_in[4];
  const float* w21  = (const float*)d_in[5];
  const float* b21  = (const float*)d_in[6];
  const float* w22  = (const float*)d_in[7];
  const float* b22  = (const float*)d_in[8];
  const float* wm1  = (const float*)d_in[9];
  const float* bm1  = (const float*)d_in[10];
  const float* wm2  = (const float*)d_in[11];
  const float* bm2  = (const float*)d_in[12];
  const float* w31  = (const float*)d_in[13];
  const float* b31  = (const float*)d_in[14];
  const float* w32  = (const float*)d_in[15];
  const float* b32  = (const float*)d_in[16];
  _Float16* ws = (_Float16*)d_ws;
  float* out = (float*)d_out;
  const int batch = in_sizes[0] / 6;

  hipLaunchKernelGGL(prepack, dim3(96), dim3(256), 0, stream,
                     w1, w21, w22, wm1, wm2, w31, w32,
                     b1, b21, b22, bm1, bm2, ws);
  hipLaunchKernelGGL(bnet_main, dim3(batch / 128), dim3(256), 0, stream,
                     x, mean, stdv, b31, b32, (const _Float16*)ws, out);
}